// Round 2
// baseline (843.020 us; speedup 1.0000x reference)
//
#include <hip/hip_runtime.h>
#include <math.h>

// Problem constants (reference: B=64, TK=512, NK=256, H=512, fp32 in/out)
constexpr int kB = 64;
constexpr int kTK = 512;
constexpr int kNK = 256;
constexpr int kH = 512;
constexpr int kTokBlocks = kB * kTK / 64;   // 512
constexpr int kNodeBlocks = kB * kNK / 64;  // 256

typedef float f32x4 __attribute__((ext_vector_type(4)));
typedef __bf16 bf16x8 __attribute__((ext_vector_type(8)));

__device__ __forceinline__ unsigned short f32_to_bf16(float f) {
  return (unsigned short)((__float_as_uint(f) + 0x8000u) >> 16);
}

__device__ __forceinline__ float tanh_fast(float x) {
  float e = __builtin_amdgcn_exp2f(x * 2.8853900817779268f);  // e^{2x}
  return 1.0f - 2.0f * __builtin_amdgcn_rcpf(e + 1.0f);
}

// CK-style: drain LDS only, leave global loads in flight across the barrier.
__device__ __forceinline__ void lds_barrier() {
  __builtin_amdgcn_s_waitcnt(0xC07F);
  __builtin_amdgcn_s_barrier();
}

// ---------------------------------------------------------- prep kernel
// blocks [0,512): W transpose->bf16 [n][k]; blocks [512,1024): dec partials.
__global__ __launch_bounds__(256) void prep_kernel(
    const float* __restrict__ Wtok, const float* __restrict__ Wnode,
    unsigned short* __restrict__ WtokT, unsigned short* __restrict__ WnodeT,
    const float* __restrict__ s_t_hat, const float* __restrict__ W_dec,
    float* __restrict__ dec_part) {
  __shared__ float sm[32 * 33];
  const int tid = threadIdx.x;
  if (blockIdx.x < 512) {
    const int idx = blockIdx.x;
    const int z = idx >> 8, rem = idx & 255;
    const int bx = rem & 15, by = rem >> 4;
    const float* W = z ? Wnode : Wtok;
    unsigned short* T = z ? WnodeT : WtokT;
    const int tx = tid & 31, ty = tid >> 5;
#pragma unroll
    for (int i = 0; i < 4; ++i)
      sm[(ty + 8 * i) * 33 + tx] =
          W[(size_t)(by * 32 + ty + 8 * i) * kH + bx * 32 + tx];
    __syncthreads();
#pragma unroll
    for (int i = 0; i < 4; ++i)
      T[(size_t)(bx * 32 + ty + 8 * i) * kH + by * 32 + tx] =
          f32_to_bf16(sm[tx * 33 + ty + 8 * i]);
  } else {
    const int r = blockIdx.x - 512;
    const int b = r >> 3, s = r & 7;
    if (tid < 128) sm[tid] = s_t_hat[(size_t)b * 1024 + s * 128 + tid];
    __syncthreads();
    float a0 = 0.f, a1 = 0.f;
    const float* w = W_dec + (size_t)(s * 128) * kH;
#pragma unroll 8
    for (int k = 0; k < 128; ++k) {
      a0 = fmaf(sm[k], w[(size_t)k * kH + tid], a0);
      a1 = fmaf(sm[k], w[(size_t)k * kH + tid + 256], a1);
    }
    dec_part[(size_t)(b * 8 + s) * kH + tid] = a0;
    dec_part[(size_t)(b * 8 + s) * kH + tid + 256] = a1;
  }
}

// ---------------------------------------------------------- fused scores
// 512 threads = 8 waves. Block tile 64 rows x 512 cols, BK=128, 4 chunks.
// Wave w owns cols [64w,64w+64): 4(m) x 4(n) tiles of mfma 16x16x32_bf16.
// Rationale vs the old 16-wave version: 8-wave blocks fit 4/CU -> the whole
// 768-block grid is co-resident (32 waves/CU), desynced across barriers,
// and each group has 16 independent MFMAs per 4 ds_read_b128 (was 8:4).
// That attacks the measured 74% no-issue stall (MfmaUtil 11 / VALU 15 /
// occupancy 42 with one 16-wave block per CU).
__global__ __launch_bounds__(512, 8) void scores_fused_kernel(
    const float* __restrict__ enc_tok, const float* __restrict__ enc_node,
    const unsigned short* __restrict__ WtokT,
    const unsigned short* __restrict__ WnodeT,
    const float* __restrict__ dec_part, const float* __restrict__ b_dec,
    const float* __restrict__ flow, const float* __restrict__ W_c,
    const float* __restrict__ v_tok, const float* __restrict__ v_node,
    float* __restrict__ scores_tok, float* __restrict__ scores_node) {
  const int tid = threadIdx.x;
  const int wave = tid >> 6, lane = tid & 63;
  const int quad = lane >> 4, l15 = lane & 15;
  const bool is_node = blockIdx.x >= kTokBlocks;
  const int bidx = is_node ? (int)blockIdx.x - kTokBlocks : (int)blockIdx.x;
  const float* A = is_node ? enc_node : enc_tok;
  const unsigned short* WT = is_node ? WnodeT : WtokT;
  const float* v = is_node ? v_node : v_tok;
  float* scores = is_node ? scores_node : scores_tok;
  const int ROWS = is_node ? kNK : kTK;
  const int b = is_node ? (bidx >> 2) : (bidx >> 3);
  const int row0 = (is_node ? (bidx & 3) : (bidx & 7)) * 64;

  __shared__ __align__(16) unsigned short As[2][8192];  // 16 KB x2
  __shared__ float red[8][64];

  const f32x4 fzero = {0.f, 0.f, 0.f, 0.f};
  f32x4 acc[4][4];
#pragma unroll
  for (int i = 0; i < 4; ++i)
#pragma unroll
    for (int j = 0; j < 4; ++j) acc[i][j] = fzero;

  // dense A staging map: thread t handles rows r=t>>4 and r+32, k-seg kcol.
  const int r = tid >> 4;      // 0..31
  const int kcol = tid & 15;   // k-segment
  const float* aptr = A + (size_t)(b * ROWS + row0 + r) * kH + kcol * 4;
  // LDS ushort addr for element (row,k): slot*8 + (k&7),
  // slot = ((k>>5)*4 + (row>>4))*64 + ((k>>3)&3)*16 + (row&15), XOR-swizzled
  // (involution on bits 1-2 by bits 4-5, bit 0 by bit 8) -> 0 write conflicts
  // (verified by counter last round).
  auto mkaddr = [](int row, int k) {
    const int s = ((k >> 5) * 4 + (row >> 4)) * 64 + ((k >> 3) & 3) * 16 + (row & 15);
    const int sw = s ^ (((s >> 4) & 3) << 1) ^ ((s >> 8) & 1);
    return sw * 8 + (k & 7);
  };
  const int k0 = kcol * 4;
  const int k1 = 64 + kcol * 4;
  const int addr00 = mkaddr(r, k0), addr01 = mkaddr(r, k1);
  const int addr10 = mkaddr(r + 32, k0), addr11 = mkaddr(r + 32, k1);

  float4 ax0, ax1, ax2, ax3;  // one chunk of A in flight
  auto aload = [&](int kc) {
    ax0 = *(const float4*)(aptr + kc * 128);
    ax1 = *(const float4*)(aptr + kc * 128 + 64);
    ax2 = *(const float4*)(aptr + (size_t)32 * kH + kc * 128);
    ax3 = *(const float4*)(aptr + (size_t)32 * kH + kc * 128 + 64);
  };
  auto commit = [&](int buf) {
    ushort4 h0, h1, h2, h3;
    h0.x = f32_to_bf16(ax0.x); h0.y = f32_to_bf16(ax0.y);
    h0.z = f32_to_bf16(ax0.z); h0.w = f32_to_bf16(ax0.w);
    h1.x = f32_to_bf16(ax1.x); h1.y = f32_to_bf16(ax1.y);
    h1.z = f32_to_bf16(ax1.z); h1.w = f32_to_bf16(ax1.w);
    h2.x = f32_to_bf16(ax2.x); h2.y = f32_to_bf16(ax2.y);
    h2.z = f32_to_bf16(ax2.z); h2.w = f32_to_bf16(ax2.w);
    h3.x = f32_to_bf16(ax3.x); h3.y = f32_to_bf16(ax3.y);
    h3.z = f32_to_bf16(ax3.z); h3.w = f32_to_bf16(ax3.w);
    *(ushort4*)&As[buf][addr00] = h0;
    *(ushort4*)&As[buf][addr01] = h1;
    *(ushort4*)&As[buf][addr10] = h2;
    *(ushort4*)&As[buf][addr11] = h3;
  };

  // B: wave owns cols [64w, 64w+64): 4 n-tiles of 16.
  const int n0 = wave * 64;
  const unsigned short* bbase = WT + (size_t)(n0 + l15) * kH + quad * 8;
  bf16x8 bbuf[2][4];  // double-buffer, prefetch distance 1 group
  auto loadB = [&](int sb, int g) {
#pragma unroll
    for (int ni = 0; ni < 4; ++ni)
      bbuf[sb][ni] = *(const bf16x8*)(bbase + (size_t)(16 * ni) * kH + g * 32);
  };

  aload(0);
  commit(0);
  aload(1);
  loadB(0, 0);
  lds_barrier();

#pragma unroll
  for (int g = 0; g < 16; ++g) {
    const int kc = g >> 2, kh = g & 3;
    if (kh == 0 && kc < 3) {
      commit((kc + 1) & 1);   // ax holds chunk kc+1 (issued a full chunk ago)
      if (kc < 2) aload(kc + 2);
    }
    if (g < 15) loadB((g + 1) & 1, g + 1);
    bf16x8 afr[4];
#pragma unroll
    for (int mi = 0; mi < 4; ++mi) {
      const int slot = ((kh * 4 + mi) * 64 + lane) ^ (((lane >> 4) & 3) << 1) ^ (kh & 1);
      afr[mi] = *(const bf16x8*)&As[kc & 1][slot * 8];
    }
    __builtin_amdgcn_s_setprio(1);
#pragma unroll
    for (int mi = 0; mi < 4; ++mi)
#pragma unroll
      for (int ni = 0; ni < 4; ++ni)
        acc[mi][ni] = __builtin_amdgcn_mfma_f32_16x16x32_bf16(
            afr[mi], bbuf[g & 1][ni], acc[mi][ni], 0, 0, 0);
    __builtin_amdgcn_s_setprio(0);
    if (kh == 3 && kc < 3) lds_barrier();
  }

  // epilogue; C/D: col = n0+16ni+l15, row = 16mi+quad*4+reg
  float dec2[4], vv2[4], wc2[4];
#pragma unroll
  for (int ni = 0; ni < 4; ++ni) {
    const int col = n0 + 16 * ni + l15;
    float d = b_dec[col];
#pragma unroll
    for (int p = 0; p < 8; ++p) d += dec_part[(size_t)(b * 8 + p) * kH + col];
    dec2[ni] = d;
    vv2[ni] = v[col];
    wc2[ni] = is_node ? W_c[col] : 0.f;
  }
#pragma unroll
  for (int mi = 0; mi < 4; ++mi) {
#pragma unroll
    for (int reg = 0; reg < 4; ++reg) {
      const int row = 16 * mi + quad * 4 + reg;
      const float fl = is_node ? flow[b * kNK + row0 + row] : 0.f;
      float p = 0.f;
#pragma unroll
      for (int ni = 0; ni < 4; ++ni)
        p += tanh_fast(fmaf(fl, wc2[ni], acc[mi][ni][reg] + dec2[ni])) * vv2[ni];
#pragma unroll
      for (int off = 1; off < 16; off <<= 1) p += __shfl_xor(p, off, 64);
      if (l15 == 0) red[wave][row] = p;
    }
  }
  __syncthreads();
  if (tid < 64) {
    float s = 0.f;
#pragma unroll
    for (int w = 0; w < 8; ++w) s += red[w][tid];
    scores[b * ROWS + row0 + tid] = s;
  }
}

// ---------------------------------------------------------- softmax/mix (+zero flow)
__device__ __forceinline__ float block_sum_512(float v, float* rbuf) {
#pragma unroll
  for (int off = 32; off >= 1; off >>= 1) v += __shfl_xor(v, off, 64);
  if ((threadIdx.x & 63) == 0) rbuf[threadIdx.x >> 6] = v;
  __syncthreads();
  float s = rbuf[0];
#pragma unroll
  for (int w = 1; w < 8; ++w) s += rbuf[w];
  __syncthreads();
  return s;
}

__global__ __launch_bounds__(512) void softmax_mix_kernel(
    const float* __restrict__ scores_node, const float* __restrict__ scores_tok,
    const int* __restrict__ node_to_token,
    const float* __restrict__ mask_tok, const float* __restrict__ mask_node,
    float* __restrict__ out_final, float* __restrict__ out_attn_node,
    float* __restrict__ out_flow) {
  const int b = blockIdx.x, tid = threadIdx.x;
  __shared__ float an_sh[kNK];
  __shared__ float rbuf[8];

  if (tid < kNK) out_flow[b * kNK + tid] = 0.f;  // init for flow2 atomics

  float en = 0.f;
  if (tid < kNK)
    en = expf(scores_node[b * kNK + tid]) * mask_node[b * kNK + tid];
  float sn = block_sum_512(en, rbuf);
  float an = en / sn;
  if (tid < kNK) {
    an_sh[tid] = an;
    out_attn_node[b * kNK + tid] = an;
  }
  __syncthreads();

  const float mt = mask_tok[b * kTK + tid];
  const int idx = node_to_token[b * kTK + tid];
  float eg = expf(an_sh[idx]) * mt;
  float sg = block_sum_512(eg, rbuf);
  float an2t = eg / sg;

  float et = expf(scores_tok[b * kTK + tid]) * mt;
  float st = block_sum_512(et, rbuf);
  float at = et / st;

  out_final[b * kTK + tid] = 0.5f * (at + an2t);
}

// ---------------------------------------------------------- ct_partial + flow1
// blocks [0,512): ct partial (b, 64-row slice s of 8): 4 sub-accumulators of
//   16 rows each, reduced in LDS -> ctp[b*8+s][512].
// blocks [512,768): one_hop partials (b, sl of 64 n-rows), float4 over m,
//   in-block reduce over nsub -> fp1[b][4][256].
__global__ __launch_bounds__(512) void ct_flow1_kernel(
    const float* __restrict__ final_attn, const float* __restrict__ enc_tok,
    const float* __restrict__ attn_node, const float* __restrict__ graph,
    float* __restrict__ ctp, float* __restrict__ fp1) {
  const int tid = threadIdx.x;
  if (blockIdx.x < 512) {
    const int b = blockIdx.x >> 3, s = blockIdx.x & 7;
    __shared__ float fa[64];
    __shared__ float part[4][512];
    if (tid < 64) fa[tid] = final_attn[b * kTK + s * 64 + tid];
    __syncthreads();
    const int h4 = (tid & 127) * 4, tsub = tid >> 7;   // 4 tsubs x 16 rows
    float4 acc = {0.f, 0.f, 0.f, 0.f};
    const float* base =
        enc_tok + ((size_t)(b * kTK + s * 64 + tsub * 16)) * kH + h4;
#pragma unroll
    for (int t = 0; t < 16; ++t) {
      float4 e = *(const float4*)(base + (size_t)t * kH);
      const float w = fa[tsub * 16 + t];
      acc.x = fmaf(w, e.x, acc.x); acc.y = fmaf(w, e.y, acc.y);
      acc.z = fmaf(w, e.z, acc.z); acc.w = fmaf(w, e.w, acc.w);
    }
    *(float4*)&part[tsub][h4] = acc;
    __syncthreads();
    if (tid < 128) {
      float4 s0 = {0.f, 0.f, 0.f, 0.f};
#pragma unroll
      for (int p = 0; p < 4; ++p) {
        float4 pp = *(const float4*)&part[p][tid * 4];
        s0.x += pp.x; s0.y += pp.y; s0.z += pp.z; s0.w += pp.w;
      }
      *(float4*)&ctp[((size_t)(b * 8 + s)) * kH + tid * 4] = s0;
    }
  } else {
    const int rr = blockIdx.x - 512;
    const int b = rr >> 2, sl = rr & 3;
    __shared__ float z[64];
    __shared__ float part[8][256];
    if (tid < 64) z[tid] = attn_node[b * kNK + sl * 64 + tid];
    __syncthreads();
    const int m4 = (tid & 63) * 4, nsub = tid >> 6;
    float4 acc = {0.f, 0.f, 0.f, 0.f};
    const float* g =
        graph + ((size_t)(b * kNK + sl * 64 + nsub * 8)) * kNK + m4;
#pragma unroll
    for (int n = 0; n < 8; ++n) {
      float4 gg = *(const float4*)(g + (size_t)n * kNK);
      const float w = z[nsub * 8 + n];
      acc.x = fmaf(w, gg.x, acc.x); acc.y = fmaf(w, gg.y, acc.y);
      acc.z = fmaf(w, gg.z, acc.z); acc.w = fmaf(w, gg.w, acc.w);
    }
    *(float4*)&part[nsub][m4] = acc;
    __syncthreads();
    if (tid < 64) {
      float4 s0 = {0.f, 0.f, 0.f, 0.f};
#pragma unroll
      for (int p = 0; p < 8; ++p) {
        float4 pp = *(const float4*)&part[p][tid * 4];
        s0.x += pp.x; s0.y += pp.y; s0.z += pp.z; s0.w += pp.w;
      }
      *(float4*)&fp1[((size_t)(b * 4 + sl)) * kNK + tid * 4] = s0;
    }
  }
}

// ---------------------------------------------------------- ct_reduce + flow 2-hop
__global__ __launch_bounds__(512) void ct_flow2_kernel(
    const float* __restrict__ ctp, const float* __restrict__ fp1,
    const float* __restrict__ attn_node, const float* __restrict__ graph,
    float* __restrict__ out_ct, float* __restrict__ out_flow) {
  const int tid = threadIdx.x;
  if (blockIdx.x < 64) {
    const int b = blockIdx.x;
    __shared__ float acc_sh[4][512];
    const int h4 = (tid & 127) * 4, part = tid >> 7;
    float4 a = {0.f, 0.f, 0.f, 0.f};
#pragma unroll
    for (int j = 0; j < 2; ++j) {
      float4 c = *(const float4*)&ctp[((size_t)(b * 8 + part * 2 + j)) * kH + h4];
      a.x += c.x; a.y += c.y; a.z += c.z; a.w += c.w;
    }
    *(float4*)&acc_sh[part][h4] = a;
    __syncthreads();
    if (tid < 128) {
      float4 s = {0.f, 0.f, 0.f, 0.f};
#pragma unroll
      for (int p = 0; p < 4; ++p) {
        float4 pp = *(const float4*)&acc_sh[p][tid * 4];
        s.x += pp.x; s.y += pp.y; s.z += pp.z; s.w += pp.w;
      }
      *(float4*)&out_ct[b * kH + tid * 4] = s;
    }
  } else {
    const int rr = blockIdx.x - 64;
    const int b = rr >> 2, sl = rr & 3;
    __shared__ float one_sh[64];
    __shared__ float part2[8][256];
    if (tid < 64) {
      const int n = sl * 64 + tid;
      float one = 0.f;
#pragma unroll
      for (int p = 0; p < 4; ++p) one += fp1[((size_t)(b * 4 + p)) * kNK + n];
      one_sh[tid] = one;
      atomicAdd(&out_flow[b * kNK + n],
                (attn_node[b * kNK + n] + one) * 0.33333f);
    }
    __syncthreads();
    const int m4 = (tid & 63) * 4, nsub = tid >> 6;
    float4 acc = {0.f, 0.f, 0.f, 0.f};
    const float* g =
        graph + ((size_t)(b * kNK + sl * 64 + nsub * 8)) * kNK + m4;
#pragma unroll
    for (int n = 0; n < 8; ++n) {
      float4 gg = *(const float4*)(g + (size_t)n * kNK);
      const float w = one_sh[sl * 0 + nsub * 8 + n];
      acc.x = fmaf(w, gg.x, acc.x); acc.y = fmaf(w, gg.y, acc.y);
      acc.z = fmaf(w, gg.z, acc.z); acc.w = fmaf(w, gg.w, acc.w);
    }
    *(float4*)&part2[nsub][m4] = acc;
    __syncthreads();
    if (tid < 64) {
      float4 s = {0.f, 0.f, 0.f, 0.f};
#pragma unroll
      for (int p = 0; p < 8; ++p) {
        float4 pp = *(const float4*)&part2[p][tid * 4];
        s.x += pp.x; s.y += pp.y; s.z += pp.z; s.w += pp.w;
      }
      float* dst = &out_flow[b * kNK + tid * 4];
      atomicAdd(dst + 0, s.x * 0.33333f);
      atomicAdd(dst + 1, s.y * 0.33333f);
      atomicAdd(dst + 2, s.z * 0.33333f);
      atomicAdd(dst + 3, s.w * 0.33333f);
    }
  }
}

// ---------------------------------------------------------------- launch
extern "C" void kernel_launch(void* const* d_in, const int* in_sizes, int n_in,
                              void* d_out, int out_size, void* d_ws, size_t ws_size,
                              hipStream_t stream) {
  (void)in_sizes; (void)n_in; (void)out_size; (void)ws_size;
  const float* s_t_hat  = (const float*)d_in[0];
  const float* enc_tok  = (const float*)d_in[1];
  const float* enc_node = (const float*)d_in[2];
  const int*   n2t      = (const int*)d_in[3];
  const float* mask_tok = (const float*)d_in[4];
  const float* mask_nd  = (const float*)d_in[5];
  const float* graph    = (const float*)d_in[6];
  const float* flow     = (const float*)d_in[7];
  const float* W_c      = (const float*)d_in[8];
  const float* W_tok    = (const float*)d_in[9];
  const float* W_node   = (const float*)d_in[10];
  const float* W_dec    = (const float*)d_in[11];
  const float* b_dec    = (const float*)d_in[12];
  const float* v_tok    = (const float*)d_in[13];
  const float* v_node   = (const float*)d_in[14];

  float* out = (float*)d_out;   // c_t | final_attn | attn_dist_node | flow_out
  float* out_ct        = out;
  float* out_final     = out + kB * kH;
  float* out_attn_node = out + 2 * kB * kH;
  float* out_flow      = out_attn_node + kB * kNK;

  // workspace (float offsets):
  float* ws = (float*)d_ws;
  float* scores_tok  = ws;                    // 32768
  float* scores_node = ws + 32768;            // 16384
  float* dec_part    = ws + 49152;            // 262144 (consumed by scores)
  float* ctp         = dec_part;              // alias: 64*8*512 = 262144
  float* fp1         = ws + 311296;           // 64*4*256 = 65536
  unsigned short* WtokT  = (unsigned short*)(ws + 376832);
  unsigned short* WnodeT = WtokT + kH * kH;

  prep_kernel<<<1024, 256, 0, stream>>>(W_tok, W_node, WtokT, WnodeT,
                                        s_t_hat, W_dec, dec_part);
  scores_fused_kernel<<<kTokBlocks + kNodeBlocks, 512, 0, stream>>>(
      enc_tok, enc_node, WtokT, WnodeT, dec_part, b_dec, flow, W_c,
      v_tok, v_node, scores_tok, scores_node);
  softmax_mix_kernel<<<kB, 512, 0, stream>>>(scores_node, scores_tok, n2t,
                                             mask_tok, mask_nd, out_final,
                                             out_attn_node, out_flow);
  ct_flow1_kernel<<<768, 512, 0, stream>>>(out_final, enc_tok, out_attn_node,
                                           graph, ctp, fp1);
  ct_flow2_kernel<<<320, 512, 0, stream>>>(ctp, fp1, out_attn_node, graph,
                                           out_ct, out_flow);
}

// Round 3
// 299.400 us; speedup vs baseline: 2.8157x; 2.8157x over previous
//
#include <hip/hip_runtime.h>
#include <math.h>

// Problem constants (reference: B=64, TK=512, NK=256, H=512, fp32 in/out)
constexpr int kB = 64;
constexpr int kTK = 512;
constexpr int kNK = 256;
constexpr int kH = 512;
constexpr int kTokBlocks = kB * kTK / 64;   // 512
constexpr int kNodeBlocks = kB * kNK / 64;  // 256

typedef float f32x4 __attribute__((ext_vector_type(4)));
typedef __bf16 bf16x8 __attribute__((ext_vector_type(8)));

__device__ __forceinline__ unsigned short f32_to_bf16(float f) {
  return (unsigned short)((__float_as_uint(f) + 0x8000u) >> 16);
}

__device__ __forceinline__ float tanh_fast(float x) {
  float e = __builtin_amdgcn_exp2f(x * 2.8853900817779268f);  // e^{2x}
  return 1.0f - 2.0f * __builtin_amdgcn_rcpf(e + 1.0f);
}

// CK-style: drain LDS only, leave global loads in flight across the barrier.
__device__ __forceinline__ void lds_barrier() {
  __builtin_amdgcn_s_waitcnt(0xC07F);
  __builtin_amdgcn_s_barrier();
}

// ---------------------------------------------------------- prep kernel
// blocks [0,512): W transpose->bf16 [n][k]; blocks [512,1024): dec partials.
__global__ __launch_bounds__(256) void prep_kernel(
    const float* __restrict__ Wtok, const float* __restrict__ Wnode,
    unsigned short* __restrict__ WtokT, unsigned short* __restrict__ WnodeT,
    const float* __restrict__ s_t_hat, const float* __restrict__ W_dec,
    float* __restrict__ dec_part) {
  __shared__ float sm[32 * 33];
  const int tid = threadIdx.x;
  if (blockIdx.x < 512) {
    const int idx = blockIdx.x;
    const int z = idx >> 8, rem = idx & 255;
    const int bx = rem & 15, by = rem >> 4;
    const float* W = z ? Wnode : Wtok;
    unsigned short* T = z ? WnodeT : WtokT;
    const int tx = tid & 31, ty = tid >> 5;
#pragma unroll
    for (int i = 0; i < 4; ++i)
      sm[(ty + 8 * i) * 33 + tx] =
          W[(size_t)(by * 32 + ty + 8 * i) * kH + bx * 32 + tx];
    __syncthreads();
#pragma unroll
    for (int i = 0; i < 4; ++i)
      T[(size_t)(bx * 32 + ty + 8 * i) * kH + by * 32 + tx] =
          f32_to_bf16(sm[tx * 33 + ty + 8 * i]);
  } else {
    const int r = blockIdx.x - 512;
    const int b = r >> 3, s = r & 7;
    if (tid < 128) sm[tid] = s_t_hat[(size_t)b * 1024 + s * 128 + tid];
    __syncthreads();
    float a0 = 0.f, a1 = 0.f;
    const float* w = W_dec + (size_t)(s * 128) * kH;
#pragma unroll 8
    for (int k = 0; k < 128; ++k) {
      a0 = fmaf(sm[k], w[(size_t)k * kH + tid], a0);
      a1 = fmaf(sm[k], w[(size_t)k * kH + tid + 256], a1);
    }
    dec_part[(size_t)(b * 8 + s) * kH + tid] = a0;
    dec_part[(size_t)(b * 8 + s) * kH + tid + 256] = a1;
  }
}

// ---------------------------------------------------------- fused scores
// 512 threads = 8 waves. Block tile 64 rows x 512 cols, BK=128, 4 chunks.
// Wave w owns cols [64w,64w+64): 4(m) x 4(n) tiles of mfma 16x16x32_bf16.
// ~114 combined VGPR+AGPR -> 4 waves/EU cap (128): 2 blocks/CU resident,
// two independent barrier domains per CU + 16 MFMAs per 4 ds_read_b128.
// NOTE round-2 lesson: __launch_bounds__ min-waves=8 capped VGPRs at 64 and
// spilled everything to scratch (FETCH 862 MB, WRITE 1.5 GB, 683 us). The
// 2nd arg must match the register budget: 4 waves/EU here.
__global__ __launch_bounds__(512, 4) void scores_fused_kernel(
    const float* __restrict__ enc_tok, const float* __restrict__ enc_node,
    const unsigned short* __restrict__ WtokT,
    const unsigned short* __restrict__ WnodeT,
    const float* __restrict__ dec_part, const float* __restrict__ b_dec,
    const float* __restrict__ flow, const float* __restrict__ W_c,
    const float* __restrict__ v_tok, const float* __restrict__ v_node,
    float* __restrict__ scores_tok, float* __restrict__ scores_node) {
  const int tid = threadIdx.x;
  const int wave = tid >> 6, lane = tid & 63;
  const int quad = lane >> 4, l15 = lane & 15;
  const bool is_node = blockIdx.x >= kTokBlocks;
  const int bidx = is_node ? (int)blockIdx.x - kTokBlocks : (int)blockIdx.x;
  const float* A = is_node ? enc_node : enc_tok;
  const unsigned short* WT = is_node ? WnodeT : WtokT;
  const float* v = is_node ? v_node : v_tok;
  float* scores = is_node ? scores_node : scores_tok;
  const int ROWS = is_node ? kNK : kTK;
  const int b = is_node ? (bidx >> 2) : (bidx >> 3);
  const int row0 = (is_node ? (bidx & 3) : (bidx & 7)) * 64;

  __shared__ __align__(16) unsigned short As[2][8192];  // 16 KB x2
  __shared__ float red[8][64];

  const f32x4 fzero = {0.f, 0.f, 0.f, 0.f};
  f32x4 acc[4][4];
#pragma unroll
  for (int i = 0; i < 4; ++i)
#pragma unroll
    for (int j = 0; j < 4; ++j) acc[i][j] = fzero;

  // dense A staging map: thread t handles rows r=t>>4 and r+32, k-seg kcol.
  const int r = tid >> 4;      // 0..31
  const int kcol = tid & 15;   // k-segment
  const float* aptr = A + (size_t)(b * ROWS + row0 + r) * kH + kcol * 4;
  // LDS ushort addr for element (row,k): slot*8 + (k&7),
  // slot = ((k>>5)*4 + (row>>4))*64 + ((k>>3)&3)*16 + (row&15), XOR-swizzled
  // (involution on bits 1-2 by bits 4-5, bit 0 by bit 8) -> 0 write conflicts
  // (verified by counter in earlier rounds).
  auto mkaddr = [](int row, int k) {
    const int s = ((k >> 5) * 4 + (row >> 4)) * 64 + ((k >> 3) & 3) * 16 + (row & 15);
    const int sw = s ^ (((s >> 4) & 3) << 1) ^ ((s >> 8) & 1);
    return sw * 8 + (k & 7);
  };
  const int k0 = kcol * 4;
  const int k1 = 64 + kcol * 4;
  const int addr00 = mkaddr(r, k0), addr01 = mkaddr(r, k1);
  const int addr10 = mkaddr(r + 32, k0), addr11 = mkaddr(r + 32, k1);

  float4 ax0, ax1, ax2, ax3;  // one chunk of A in flight
  auto aload = [&](int kc) {
    ax0 = *(const float4*)(aptr + kc * 128);
    ax1 = *(const float4*)(aptr + kc * 128 + 64);
    ax2 = *(const float4*)(aptr + (size_t)32 * kH + kc * 128);
    ax3 = *(const float4*)(aptr + (size_t)32 * kH + kc * 128 + 64);
  };
  auto commit = [&](int buf) {
    ushort4 h0, h1, h2, h3;
    h0.x = f32_to_bf16(ax0.x); h0.y = f32_to_bf16(ax0.y);
    h0.z = f32_to_bf16(ax0.z); h0.w = f32_to_bf16(ax0.w);
    h1.x = f32_to_bf16(ax1.x); h1.y = f32_to_bf16(ax1.y);
    h1.z = f32_to_bf16(ax1.z); h1.w = f32_to_bf16(ax1.w);
    h2.x = f32_to_bf16(ax2.x); h2.y = f32_to_bf16(ax2.y);
    h2.z = f32_to_bf16(ax2.z); h2.w = f32_to_bf16(ax2.w);
    h3.x = f32_to_bf16(ax3.x); h3.y = f32_to_bf16(ax3.y);
    h3.z = f32_to_bf16(ax3.z); h3.w = f32_to_bf16(ax3.w);
    *(ushort4*)&As[buf][addr00] = h0;
    *(ushort4*)&As[buf][addr01] = h1;
    *(ushort4*)&As[buf][addr10] = h2;
    *(ushort4*)&As[buf][addr11] = h3;
  };

  // B: wave owns cols [64w, 64w+64): 4 n-tiles of 16.
  const int n0 = wave * 64;
  const unsigned short* bbase = WT + (size_t)(n0 + l15) * kH + quad * 8;
  bf16x8 bbuf[2][4];  // double-buffer, prefetch distance 1 group
  auto loadB = [&](int sb, int g) {
#pragma unroll
    for (int ni = 0; ni < 4; ++ni)
      bbuf[sb][ni] = *(const bf16x8*)(bbase + (size_t)(16 * ni) * kH + g * 32);
  };

  aload(0);
  commit(0);
  aload(1);
  loadB(0, 0);
  lds_barrier();

#pragma unroll
  for (int g = 0; g < 16; ++g) {
    const int kc = g >> 2, kh = g & 3;
    if (kh == 0 && kc < 3) {
      commit((kc + 1) & 1);   // ax holds chunk kc+1 (issued a full chunk ago)
      if (kc < 2) aload(kc + 2);
    }
    if (g < 15) loadB((g + 1) & 1, g + 1);
    bf16x8 afr[4];
#pragma unroll
    for (int mi = 0; mi < 4; ++mi) {
      const int slot = ((kh * 4 + mi) * 64 + lane) ^ (((lane >> 4) & 3) << 1) ^ (kh & 1);
      afr[mi] = *(const bf16x8*)&As[kc & 1][slot * 8];
    }
    __builtin_amdgcn_s_setprio(1);
#pragma unroll
    for (int mi = 0; mi < 4; ++mi)
#pragma unroll
      for (int ni = 0; ni < 4; ++ni)
        acc[mi][ni] = __builtin_amdgcn_mfma_f32_16x16x32_bf16(
            afr[mi], bbuf[g & 1][ni], acc[mi][ni], 0, 0, 0);
    __builtin_amdgcn_s_setprio(0);
    if (kh == 3 && kc < 3) lds_barrier();
  }

  // epilogue; C/D: col = n0+16ni+l15, row = 16mi+quad*4+reg
  float dec2[4], vv2[4], wc2[4];
#pragma unroll
  for (int ni = 0; ni < 4; ++ni) {
    const int col = n0 + 16 * ni + l15;
    float d = b_dec[col];
#pragma unroll
    for (int p = 0; p < 8; ++p) d += dec_part[(size_t)(b * 8 + p) * kH + col];
    dec2[ni] = d;
    vv2[ni] = v[col];
    wc2[ni] = is_node ? W_c[col] : 0.f;
  }
#pragma unroll
  for (int mi = 0; mi < 4; ++mi) {
#pragma unroll
    for (int reg = 0; reg < 4; ++reg) {
      const int row = 16 * mi + quad * 4 + reg;
      const float fl = is_node ? flow[b * kNK + row0 + row] : 0.f;
      float p = 0.f;
#pragma unroll
      for (int ni = 0; ni < 4; ++ni)
        p += tanh_fast(fmaf(fl, wc2[ni], acc[mi][ni][reg] + dec2[ni])) * vv2[ni];
#pragma unroll
      for (int off = 1; off < 16; off <<= 1) p += __shfl_xor(p, off, 64);
      if (l15 == 0) red[wave][row] = p;
    }
  }
  __syncthreads();
  if (tid < 64) {
    float s = 0.f;
#pragma unroll
    for (int w = 0; w < 8; ++w) s += red[w][tid];
    scores[b * ROWS + row0 + tid] = s;
  }
}

// ---------------------------------------------------------- softmax/mix (+zero flow)
__device__ __forceinline__ float block_sum_512(float v, float* rbuf) {
#pragma unroll
  for (int off = 32; off >= 1; off >>= 1) v += __shfl_xor(v, off, 64);
  if ((threadIdx.x & 63) == 0) rbuf[threadIdx.x >> 6] = v;
  __syncthreads();
  float s = rbuf[0];
#pragma unroll
  for (int w = 1; w < 8; ++w) s += rbuf[w];
  __syncthreads();
  return s;
}

__global__ __launch_bounds__(512) void softmax_mix_kernel(
    const float* __restrict__ scores_node, const float* __restrict__ scores_tok,
    const int* __restrict__ node_to_token,
    const float* __restrict__ mask_tok, const float* __restrict__ mask_node,
    float* __restrict__ out_final, float* __restrict__ out_attn_node,
    float* __restrict__ out_flow) {
  const int b = blockIdx.x, tid = threadIdx.x;
  __shared__ float an_sh[kNK];
  __shared__ float rbuf[8];

  if (tid < kNK) out_flow[b * kNK + tid] = 0.f;  // init for flow2 atomics

  float en = 0.f;
  if (tid < kNK)
    en = expf(scores_node[b * kNK + tid]) * mask_node[b * kNK + tid];
  float sn = block_sum_512(en, rbuf);
  float an = en / sn;
  if (tid < kNK) {
    an_sh[tid] = an;
    out_attn_node[b * kNK + tid] = an;
  }
  __syncthreads();

  const float mt = mask_tok[b * kTK + tid];
  const int idx = node_to_token[b * kTK + tid];
  float eg = expf(an_sh[idx]) * mt;
  float sg = block_sum_512(eg, rbuf);
  float an2t = eg / sg;

  float et = expf(scores_tok[b * kTK + tid]) * mt;
  float st = block_sum_512(et, rbuf);
  float at = et / st;

  out_final[b * kTK + tid] = 0.5f * (at + an2t);
}

// ---------------------------------------------------------- ct_partial + flow1
// blocks [0,512): ct partial (b, 64-row slice s of 8): 4 sub-accumulators of
//   16 rows each, reduced in LDS -> ctp[b*8+s][512].
// blocks [512,768): one_hop partials (b, sl of 64 n-rows), float4 over m,
//   in-block reduce over nsub -> fp1[b][4][256].
__global__ __launch_bounds__(512) void ct_flow1_kernel(
    const float* __restrict__ final_attn, const float* __restrict__ enc_tok,
    const float* __restrict__ attn_node, const float* __restrict__ graph,
    float* __restrict__ ctp, float* __restrict__ fp1) {
  const int tid = threadIdx.x;
  if (blockIdx.x < 512) {
    const int b = blockIdx.x >> 3, s = blockIdx.x & 7;
    __shared__ float fa[64];
    __shared__ float part[4][512];
    if (tid < 64) fa[tid] = final_attn[b * kTK + s * 64 + tid];
    __syncthreads();
    const int h4 = (tid & 127) * 4, tsub = tid >> 7;   // 4 tsubs x 16 rows
    float4 acc = {0.f, 0.f, 0.f, 0.f};
    const float* base =
        enc_tok + ((size_t)(b * kTK + s * 64 + tsub * 16)) * kH + h4;
#pragma unroll
    for (int t = 0; t < 16; ++t) {
      float4 e = *(const float4*)(base + (size_t)t * kH);
      const float w = fa[tsub * 16 + t];
      acc.x = fmaf(w, e.x, acc.x); acc.y = fmaf(w, e.y, acc.y);
      acc.z = fmaf(w, e.z, acc.z); acc.w = fmaf(w, e.w, acc.w);
    }
    *(float4*)&part[tsub][h4] = acc;
    __syncthreads();
    if (tid < 128) {
      float4 s0 = {0.f, 0.f, 0.f, 0.f};
#pragma unroll
      for (int p = 0; p < 4; ++p) {
        float4 pp = *(const float4*)&part[p][tid * 4];
        s0.x += pp.x; s0.y += pp.y; s0.z += pp.z; s0.w += pp.w;
      }
      *(float4*)&ctp[((size_t)(b * 8 + s)) * kH + tid * 4] = s0;
    }
  } else {
    const int rr = blockIdx.x - 512;
    const int b = rr >> 2, sl = rr & 3;
    __shared__ float z[64];
    __shared__ float part[8][256];
    if (tid < 64) z[tid] = attn_node[b * kNK + sl * 64 + tid];
    __syncthreads();
    const int m4 = (tid & 63) * 4, nsub = tid >> 6;
    float4 acc = {0.f, 0.f, 0.f, 0.f};
    const float* g =
        graph + ((size_t)(b * kNK + sl * 64 + nsub * 8)) * kNK + m4;
#pragma unroll
    for (int n = 0; n < 8; ++n) {
      float4 gg = *(const float4*)(g + (size_t)n * kNK);
      const float w = z[nsub * 8 + n];
      acc.x = fmaf(w, gg.x, acc.x); acc.y = fmaf(w, gg.y, acc.y);
      acc.z = fmaf(w, gg.z, acc.z); acc.w = fmaf(w, gg.w, acc.w);
    }
    *(float4*)&part[nsub][m4] = acc;
    __syncthreads();
    if (tid < 64) {
      float4 s0 = {0.f, 0.f, 0.f, 0.f};
#pragma unroll
      for (int p = 0; p < 8; ++p) {
        float4 pp = *(const float4*)&part[p][tid * 4];
        s0.x += pp.x; s0.y += pp.y; s0.z += pp.z; s0.w += pp.w;
      }
      *(float4*)&fp1[((size_t)(b * 4 + sl)) * kNK + tid * 4] = s0;
    }
  }
}

// ---------------------------------------------------------- ct_reduce + flow 2-hop
__global__ __launch_bounds__(512) void ct_flow2_kernel(
    const float* __restrict__ ctp, const float* __restrict__ fp1,
    const float* __restrict__ attn_node, const float* __restrict__ graph,
    float* __restrict__ out_ct, float* __restrict__ out_flow) {
  const int tid = threadIdx.x;
  if (blockIdx.x < 64) {
    const int b = blockIdx.x;
    __shared__ float acc_sh[4][512];
    const int h4 = (tid & 127) * 4, part = tid >> 7;
    float4 a = {0.f, 0.f, 0.f, 0.f};
#pragma unroll
    for (int j = 0; j < 2; ++j) {
      float4 c = *(const float4*)&ctp[((size_t)(b * 8 + part * 2 + j)) * kH + h4];
      a.x += c.x; a.y += c.y; a.z += c.z; a.w += c.w;
    }
    *(float4*)&acc_sh[part][h4] = a;
    __syncthreads();
    if (tid < 128) {
      float4 s = {0.f, 0.f, 0.f, 0.f};
#pragma unroll
      for (int p = 0; p < 4; ++p) {
        float4 pp = *(const float4*)&acc_sh[p][tid * 4];
        s.x += pp.x; s.y += pp.y; s.z += pp.z; s.w += pp.w;
      }
      *(float4*)&out_ct[b * kH + tid * 4] = s;
    }
  } else {
    const int rr = blockIdx.x - 64;
    const int b = rr >> 2, sl = rr & 3;
    __shared__ float one_sh[64];
    __shared__ float part2[8][256];
    if (tid < 64) {
      const int n = sl * 64 + tid;
      float one = 0.f;
#pragma unroll
      for (int p = 0; p < 4; ++p) one += fp1[((size_t)(b * 4 + p)) * kNK + n];
      one_sh[tid] = one;
      atomicAdd(&out_flow[b * kNK + n],
                (attn_node[b * kNK + n] + one) * 0.33333f);
    }
    __syncthreads();
    const int m4 = (tid & 63) * 4, nsub = tid >> 6;
    float4 acc = {0.f, 0.f, 0.f, 0.f};
    const float* g =
        graph + ((size_t)(b * kNK + sl * 64 + nsub * 8)) * kNK + m4;
#pragma unroll
    for (int n = 0; n < 8; ++n) {
      float4 gg = *(const float4*)(g + (size_t)n * kNK);
      const float w = one_sh[sl * 0 + nsub * 8 + n];
      acc.x = fmaf(w, gg.x, acc.x); acc.y = fmaf(w, gg.y, acc.y);
      acc.z = fmaf(w, gg.z, acc.z); acc.w = fmaf(w, gg.w, acc.w);
    }
    *(float4*)&part2[nsub][m4] = acc;
    __syncthreads();
    if (tid < 64) {
      float4 s = {0.f, 0.f, 0.f, 0.f};
#pragma unroll
      for (int p = 0; p < 8; ++p) {
        float4 pp = *(const float4*)&part2[p][tid * 4];
        s.x += pp.x; s.y += pp.y; s.z += pp.z; s.w += pp.w;
      }
      float* dst = &out_flow[b * kNK + tid * 4];
      atomicAdd(dst + 0, s.x * 0.33333f);
      atomicAdd(dst + 1, s.y * 0.33333f);
      atomicAdd(dst + 2, s.z * 0.33333f);
      atomicAdd(dst + 3, s.w * 0.33333f);
    }
  }
}

// ---------------------------------------------------------------- launch
extern "C" void kernel_launch(void* const* d_in, const int* in_sizes, int n_in,
                              void* d_out, int out_size, void* d_ws, size_t ws_size,
                              hipStream_t stream) {
  (void)in_sizes; (void)n_in; (void)out_size; (void)ws_size;
  const float* s_t_hat  = (const float*)d_in[0];
  const float* enc_tok  = (const float*)d_in[1];
  const float* enc_node = (const float*)d_in[2];
  const int*   n2t      = (const int*)d_in[3];
  const float* mask_tok = (const float*)d_in[4];
  const float* mask_nd  = (const float*)d_in[5];
  const float* graph    = (const float*)d_in[6];
  const float* flow     = (const float*)d_in[7];
  const float* W_c      = (const float*)d_in[8];
  const float* W_tok    = (const float*)d_in[9];
  const float* W_node   = (const float*)d_in[10];
  const float* W_dec    = (const float*)d_in[11];
  const float* b_dec    = (const float*)d_in[12];
  const float* v_tok    = (const float*)d_in[13];
  const float* v_node   = (const float*)d_in[14];

  float* out = (float*)d_out;   // c_t | final_attn | attn_dist_node | flow_out
  float* out_ct        = out;
  float* out_final     = out + kB * kH;
  float* out_attn_node = out + 2 * kB * kH;
  float* out_flow      = out_attn_node + kB * kNK;

  // workspace (float offsets):
  float* ws = (float*)d_ws;
  float* scores_tok  = ws;                    // 32768
  float* scores_node = ws + 32768;            // 16384
  float* dec_part    = ws + 49152;            // 262144 (consumed by scores)
  float* ctp         = dec_part;              // alias: 64*8*512 = 262144
  float* fp1         = ws + 311296;           // 64*4*256 = 65536
  unsigned short* WtokT  = (unsigned short*)(ws + 376832);
  unsigned short* WnodeT = WtokT + kH * kH;

  prep_kernel<<<1024, 256, 0, stream>>>(W_tok, W_node, WtokT, WnodeT,
                                        s_t_hat, W_dec, dec_part);
  scores_fused_kernel<<<kTokBlocks + kNodeBlocks, 512, 0, stream>>>(
      enc_tok, enc_node, WtokT, WnodeT, dec_part, b_dec, flow, W_c,
      v_tok, v_node, scores_tok, scores_node);
  softmax_mix_kernel<<<kB, 512, 0, stream>>>(scores_node, scores_tok, n2t,
                                             mask_tok, mask_nd, out_final,
                                             out_attn_node, out_flow);
  ct_flow1_kernel<<<768, 512, 0, stream>>>(out_final, enc_tok, out_attn_node,
                                           graph, ctp, fp1);
  ct_flow2_kernel<<<320, 512, 0, stream>>>(ctp, fp1, out_attn_node, graph,
                                           out_ct, out_flow);
}

// Round 4
// 235.905 us; speedup vs baseline: 3.5736x; 1.2692x over previous
//
#include <hip/hip_runtime.h>
#include <math.h>

// Problem constants (reference: B=64, TK=512, NK=256, H=512, fp32 in/out)
constexpr int kB = 64;
constexpr int kTK = 512;
constexpr int kNK = 256;
constexpr int kH = 512;
constexpr int kTokBlocks = kB * kTK / 64;   // 512
constexpr int kNodeBlocks = kB * kNK / 64;  // 256

typedef float f32x4 __attribute__((ext_vector_type(4)));
typedef __bf16 bf16x8 __attribute__((ext_vector_type(8)));

__device__ __forceinline__ unsigned short f32_to_bf16(float f) {
  return (unsigned short)((__float_as_uint(f) + 0x8000u) >> 16);
}

__device__ __forceinline__ float tanh_fast(float x) {
  float e = __builtin_amdgcn_exp2f(x * 2.8853900817779268f);  // e^{2x}
  return 1.0f - 2.0f * __builtin_amdgcn_rcpf(e + 1.0f);
}

// CK-style: drain LDS only, leave global loads in flight across the barrier.
__device__ __forceinline__ void lds_barrier() {
  __builtin_amdgcn_s_waitcnt(0xC07F);
  __builtin_amdgcn_s_barrier();
}

// ---------------------------------------------------------- prep kernel
// blocks [0,512): W transpose->bf16 [n][k]; blocks [512,1024): dec partials.
__global__ __launch_bounds__(256) void prep_kernel(
    const float* __restrict__ Wtok, const float* __restrict__ Wnode,
    unsigned short* __restrict__ WtokT, unsigned short* __restrict__ WnodeT,
    const float* __restrict__ s_t_hat, const float* __restrict__ W_dec,
    float* __restrict__ dec_part) {
  __shared__ float sm[32 * 33];
  const int tid = threadIdx.x;
  if (blockIdx.x < 512) {
    const int idx = blockIdx.x;
    const int z = idx >> 8, rem = idx & 255;
    const int bx = rem & 15, by = rem >> 4;
    const float* W = z ? Wnode : Wtok;
    unsigned short* T = z ? WnodeT : WtokT;
    const int tx = tid & 31, ty = tid >> 5;
#pragma unroll
    for (int i = 0; i < 4; ++i)
      sm[(ty + 8 * i) * 33 + tx] =
          W[(size_t)(by * 32 + ty + 8 * i) * kH + bx * 32 + tx];
    __syncthreads();
#pragma unroll
    for (int i = 0; i < 4; ++i)
      T[(size_t)(bx * 32 + ty + 8 * i) * kH + by * 32 + tx] =
          f32_to_bf16(sm[tx * 33 + ty + 8 * i]);
  } else {
    const int r = blockIdx.x - 512;
    const int b = r >> 3, s = r & 7;
    if (tid < 128) sm[tid] = s_t_hat[(size_t)b * 1024 + s * 128 + tid];
    __syncthreads();
    float a0 = 0.f, a1 = 0.f;
    const float* w = W_dec + (size_t)(s * 128) * kH;
#pragma unroll 8
    for (int k = 0; k < 128; ++k) {
      a0 = fmaf(sm[k], w[(size_t)k * kH + tid], a0);
      a1 = fmaf(sm[k], w[(size_t)k * kH + tid + 256], a1);
    }
    dec_part[(size_t)(b * 8 + s) * kH + tid] = a0;
    dec_part[(size_t)(b * 8 + s) * kH + tid + 256] = a1;
  }
}

// ---------------------------------------------------------- fused scores
// 512 threads = 8 waves. Block tile 64 rows x 512 cols, BK=64, 8 chunks.
// Wave w owns cols [64w,64w+64): 4(m) x 4(n) tiles of mfma 16x16x32_bf16.
// Register budget is the whole game (round 2/3 lesson): combined cap at
// __launch_bounds__(512,4) is 128. acc 64 (AGPR) + bbuf[2][2] 16 + ax 8
// + afr 16 (transient) + addressing ~15 ≈ 119 -> fits, no scratch.
// BK=64 halves A staging regs and LDS (2 x 8 KB); B is split into two
// n-phases per group with a 2-set ring (prefetch distance = 8 MFMAs, B is
// L2-resident). Target: 2 blocks/CU = 16 waves in 2 desynced barrier
// domains + 16 MFMAs per 4 ds_read_b128.
__global__ __launch_bounds__(512, 4) void scores_fused_kernel(
    const float* __restrict__ enc_tok, const float* __restrict__ enc_node,
    const unsigned short* __restrict__ WtokT,
    const unsigned short* __restrict__ WnodeT,
    const float* __restrict__ dec_part, const float* __restrict__ b_dec,
    const float* __restrict__ flow, const float* __restrict__ W_c,
    const float* __restrict__ v_tok, const float* __restrict__ v_node,
    float* __restrict__ scores_tok, float* __restrict__ scores_node) {
  const int tid = threadIdx.x;
  const int wave = tid >> 6, lane = tid & 63;
  const int quad = lane >> 4, l15 = lane & 15;
  const bool is_node = blockIdx.x >= kTokBlocks;
  const int bidx = is_node ? (int)blockIdx.x - kTokBlocks : (int)blockIdx.x;
  const float* A = is_node ? enc_node : enc_tok;
  const unsigned short* WT = is_node ? WnodeT : WtokT;
  const float* v = is_node ? v_node : v_tok;
  float* scores = is_node ? scores_node : scores_tok;
  const int ROWS = is_node ? kNK : kTK;
  const int b = is_node ? (bidx >> 2) : (bidx >> 3);
  const int row0 = (is_node ? (bidx & 3) : (bidx & 7)) * 64;

  __shared__ __align__(16) unsigned short As[2][4096];  // 8 KB x2
  __shared__ float red[8][64];

  const f32x4 fzero = {0.f, 0.f, 0.f, 0.f};
  f32x4 acc[4][4];
#pragma unroll
  for (int i = 0; i < 4; ++i)
#pragma unroll
    for (int j = 0; j < 4; ++j) acc[i][j] = fzero;

  // dense A staging map: thread t stages rows r=t>>4 and r+32, k-seg kcol
  // (one float4 each per BK=64 chunk).
  const int r = tid >> 4;      // 0..31
  const int kcol = tid & 15;   // k-segment, k0 = 4*kcol in [0,64)
  const float* aptr = A + (size_t)(b * ROWS + row0 + r) * kH + kcol * 4;
  // LDS ushort addr for element (row,k): slot*8 + (k&7),
  // slot = ((k>>5)*4 + (row>>4))*64 + ((k>>3)&3)*16 + (row&15), XOR-swizzled
  // (involution on bits 1-2 by bits 4-5, bit 0 by bit 8). This is exactly the
  // addr00/addr10 pair of the round-3 map, measured 0 bank conflicts.
  auto mkaddr = [](int row, int k) {
    const int s = ((k >> 5) * 4 + (row >> 4)) * 64 + ((k >> 3) & 3) * 16 + (row & 15);
    const int sw = s ^ (((s >> 4) & 3) << 1) ^ ((s >> 8) & 1);
    return sw * 8 + (k & 7);
  };
  const int k0 = kcol * 4;
  const int addr0 = mkaddr(r, k0);
  const int addr1 = mkaddr(r + 32, k0);

  float4 ax0, ax1;  // one BK=64 chunk of A in flight (8 regs)
  auto aload = [&](int kc) {
    ax0 = *(const float4*)(aptr + kc * 64);
    ax1 = *(const float4*)(aptr + (size_t)32 * kH + kc * 64);
  };
  auto commit = [&](int buf) {
    ushort4 h0, h1;
    h0.x = f32_to_bf16(ax0.x); h0.y = f32_to_bf16(ax0.y);
    h0.z = f32_to_bf16(ax0.z); h0.w = f32_to_bf16(ax0.w);
    h1.x = f32_to_bf16(ax1.x); h1.y = f32_to_bf16(ax1.y);
    h1.z = f32_to_bf16(ax1.z); h1.w = f32_to_bf16(ax1.w);
    *(ushort4*)&As[buf][addr0] = h0;
    *(ushort4*)&As[buf][addr1] = h1;
  };

  // B: wave owns cols [64w, 64w+64): 4 n-tiles of 16, consumed in 2 phases.
  const int n0 = wave * 64;
  const unsigned short* bbase = WT + (size_t)(n0 + l15) * kH + quad * 8;
  bf16x8 bbuf[2][2];  // set0 = n-tiles {0,1}, set1 = n-tiles {2,3}
  auto loadB = [&](int sb, int g, int half) {
    bbuf[sb][0] = *(const bf16x8*)(bbase + (size_t)(16 * (2 * half + 0)) * kH + g * 32);
    bbuf[sb][1] = *(const bf16x8*)(bbase + (size_t)(16 * (2 * half + 1)) * kH + g * 32);
  };

  aload(0);
  commit(0);
  aload(1);
  loadB(0, 0, 0);
  loadB(1, 0, 1);
  lds_barrier();

#pragma unroll
  for (int g = 0; g < 16; ++g) {
    const int kc = g >> 1, kh = g & 1;
    if (kh == 0 && kc < 7) {
      commit((kc + 1) & 1);   // ax holds chunk kc+1 (issued a full chunk ago)
      if (kc < 6) aload(kc + 2);
    }
    bf16x8 afr[4];
#pragma unroll
    for (int mi = 0; mi < 4; ++mi) {
      const int slot = ((kh * 4 + mi) * 64 + lane) ^ (((lane >> 4) & 3) << 1) ^ (kh & 1);
      afr[mi] = *(const bf16x8*)&As[kc & 1][slot * 8];
    }
    // phase 0: n-tiles 0,1 from set0; refill set1 with (g, phase1)
    if (g > 0) loadB(1, g, 1);
    __builtin_amdgcn_s_setprio(1);
#pragma unroll
    for (int mi = 0; mi < 4; ++mi)
#pragma unroll
      for (int ni = 0; ni < 2; ++ni)
        acc[mi][ni] = __builtin_amdgcn_mfma_f32_16x16x32_bf16(
            afr[mi], bbuf[0][ni], acc[mi][ni], 0, 0, 0);
    __builtin_amdgcn_s_setprio(0);
    // phase 1: n-tiles 2,3 from set1; refill set0 with (g+1, phase0)
    if (g < 15) loadB(0, g + 1, 0);
    __builtin_amdgcn_s_setprio(1);
#pragma unroll
    for (int mi = 0; mi < 4; ++mi)
#pragma unroll
      for (int ni = 0; ni < 2; ++ni)
        acc[mi][ni + 2] = __builtin_amdgcn_mfma_f32_16x16x32_bf16(
            afr[mi], bbuf[1][ni], acc[mi][ni + 2], 0, 0, 0);
    __builtin_amdgcn_s_setprio(0);
    if (kh == 1 && kc < 7) lds_barrier();
  }

  // epilogue; C/D: col = n0+16ni+l15, row = 16mi+quad*4+reg
  float dec2[4], vv2[4], wc2[4];
#pragma unroll
  for (int ni = 0; ni < 4; ++ni) {
    const int col = n0 + 16 * ni + l15;
    float d = b_dec[col];
#pragma unroll
    for (int p = 0; p < 8; ++p) d += dec_part[(size_t)(b * 8 + p) * kH + col];
    dec2[ni] = d;
    vv2[ni] = v[col];
    wc2[ni] = is_node ? W_c[col] : 0.f;
  }
#pragma unroll
  for (int mi = 0; mi < 4; ++mi) {
#pragma unroll
    for (int reg = 0; reg < 4; ++reg) {
      const int row = 16 * mi + quad * 4 + reg;
      const float fl = is_node ? flow[b * kNK + row0 + row] : 0.f;
      float p = 0.f;
#pragma unroll
      for (int ni = 0; ni < 4; ++ni)
        p += tanh_fast(fmaf(fl, wc2[ni], acc[mi][ni][reg] + dec2[ni])) * vv2[ni];
#pragma unroll
      for (int off = 1; off < 16; off <<= 1) p += __shfl_xor(p, off, 64);
      if (l15 == 0) red[wave][row] = p;
    }
  }
  __syncthreads();
  if (tid < 64) {
    float s = 0.f;
#pragma unroll
    for (int w = 0; w < 8; ++w) s += red[w][tid];
    scores[b * ROWS + row0 + tid] = s;
  }
}

// ---------------------------------------------------------- softmax/mix (+zero flow)
__device__ __forceinline__ float block_sum_512(float v, float* rbuf) {
#pragma unroll
  for (int off = 32; off >= 1; off >>= 1) v += __shfl_xor(v, off, 64);
  if ((threadIdx.x & 63) == 0) rbuf[threadIdx.x >> 6] = v;
  __syncthreads();
  float s = rbuf[0];
#pragma unroll
  for (int w = 1; w < 8; ++w) s += rbuf[w];
  __syncthreads();
  return s;
}

__global__ __launch_bounds__(512) void softmax_mix_kernel(
    const float* __restrict__ scores_node, const float* __restrict__ scores_tok,
    const int* __restrict__ node_to_token,
    const float* __restrict__ mask_tok, const float* __restrict__ mask_node,
    float* __restrict__ out_final, float* __restrict__ out_attn_node,
    float* __restrict__ out_flow) {
  const int b = blockIdx.x, tid = threadIdx.x;
  __shared__ float an_sh[kNK];
  __shared__ float rbuf[8];

  if (tid < kNK) out_flow[b * kNK + tid] = 0.f;  // init for flow2 atomics

  float en = 0.f;
  if (tid < kNK)
    en = expf(scores_node[b * kNK + tid]) * mask_node[b * kNK + tid];
  float sn = block_sum_512(en, rbuf);
  float an = en / sn;
  if (tid < kNK) {
    an_sh[tid] = an;
    out_attn_node[b * kNK + tid] = an;
  }
  __syncthreads();

  const float mt = mask_tok[b * kTK + tid];
  const int idx = node_to_token[b * kTK + tid];
  float eg = expf(an_sh[idx]) * mt;
  float sg = block_sum_512(eg, rbuf);
  float an2t = eg / sg;

  float et = expf(scores_tok[b * kTK + tid]) * mt;
  float st = block_sum_512(et, rbuf);
  float at = et / st;

  out_final[b * kTK + tid] = 0.5f * (at + an2t);
}

// ---------------------------------------------------------- ct_partial + flow1
// blocks [0,512): ct partial (b, 64-row slice s of 8): 4 sub-accumulators of
//   16 rows each, reduced in LDS -> ctp[b*8+s][512].
// blocks [512,768): one_hop partials (b, sl of 64 n-rows), float4 over m,
//   in-block reduce over nsub -> fp1[b][4][256].
__global__ __launch_bounds__(512) void ct_flow1_kernel(
    const float* __restrict__ final_attn, const float* __restrict__ enc_tok,
    const float* __restrict__ attn_node, const float* __restrict__ graph,
    float* __restrict__ ctp, float* __restrict__ fp1) {
  const int tid = threadIdx.x;
  if (blockIdx.x < 512) {
    const int b = blockIdx.x >> 3, s = blockIdx.x & 7;
    __shared__ float fa[64];
    __shared__ float part[4][512];
    if (tid < 64) fa[tid] = final_attn[b * kTK + s * 64 + tid];
    __syncthreads();
    const int h4 = (tid & 127) * 4, tsub = tid >> 7;   // 4 tsubs x 16 rows
    float4 acc = {0.f, 0.f, 0.f, 0.f};
    const float* base =
        enc_tok + ((size_t)(b * kTK + s * 64 + tsub * 16)) * kH + h4;
#pragma unroll
    for (int t = 0; t < 16; ++t) {
      float4 e = *(const float4*)(base + (size_t)t * kH);
      const float w = fa[tsub * 16 + t];
      acc.x = fmaf(w, e.x, acc.x); acc.y = fmaf(w, e.y, acc.y);
      acc.z = fmaf(w, e.z, acc.z); acc.w = fmaf(w, e.w, acc.w);
    }
    *(float4*)&part[tsub][h4] = acc;
    __syncthreads();
    if (tid < 128) {
      float4 s0 = {0.f, 0.f, 0.f, 0.f};
#pragma unroll
      for (int p = 0; p < 4; ++p) {
        float4 pp = *(const float4*)&part[p][tid * 4];
        s0.x += pp.x; s0.y += pp.y; s0.z += pp.z; s0.w += pp.w;
      }
      *(float4*)&ctp[((size_t)(b * 8 + s)) * kH + tid * 4] = s0;
    }
  } else {
    const int rr = blockIdx.x - 512;
    const int b = rr >> 2, sl = rr & 3;
    __shared__ float z[64];
    __shared__ float part[8][256];
    if (tid < 64) z[tid] = attn_node[b * kNK + sl * 64 + tid];
    __syncthreads();
    const int m4 = (tid & 63) * 4, nsub = tid >> 6;
    float4 acc = {0.f, 0.f, 0.f, 0.f};
    const float* g =
        graph + ((size_t)(b * kNK + sl * 64 + nsub * 8)) * kNK + m4;
#pragma unroll
    for (int n = 0; n < 8; ++n) {
      float4 gg = *(const float4*)(g + (size_t)n * kNK);
      const float w = z[nsub * 8 + n];
      acc.x = fmaf(w, gg.x, acc.x); acc.y = fmaf(w, gg.y, acc.y);
      acc.z = fmaf(w, gg.z, acc.z); acc.w = fmaf(w, gg.w, acc.w);
    }
    *(float4*)&part[nsub][m4] = acc;
    __syncthreads();
    if (tid < 64) {
      float4 s0 = {0.f, 0.f, 0.f, 0.f};
#pragma unroll
      for (int p = 0; p < 8; ++p) {
        float4 pp = *(const float4*)&part[p][tid * 4];
        s0.x += pp.x; s0.y += pp.y; s0.z += pp.z; s0.w += pp.w;
      }
      *(float4*)&fp1[((size_t)(b * 4 + sl)) * kNK + tid * 4] = s0;
    }
  }
}

// ---------------------------------------------------------- ct_reduce + flow 2-hop
__global__ __launch_bounds__(512) void ct_flow2_kernel(
    const float* __restrict__ ctp, const float* __restrict__ fp1,
    const float* __restrict__ attn_node, const float* __restrict__ graph,
    float* __restrict__ out_ct, float* __restrict__ out_flow) {
  const int tid = threadIdx.x;
  if (blockIdx.x < 64) {
    const int b = blockIdx.x;
    __shared__ float acc_sh[4][512];
    const int h4 = (tid & 127) * 4, part = tid >> 7;
    float4 a = {0.f, 0.f, 0.f, 0.f};
#pragma unroll
    for (int j = 0; j < 2; ++j) {
      float4 c = *(const float4*)&ctp[((size_t)(b * 8 + part * 2 + j)) * kH + h4];
      a.x += c.x; a.y += c.y; a.z += c.z; a.w += c.w;
    }
    *(float4*)&acc_sh[part][h4] = a;
    __syncthreads();
    if (tid < 128) {
      float4 s = {0.f, 0.f, 0.f, 0.f};
#pragma unroll
      for (int p = 0; p < 4; ++p) {
        float4 pp = *(const float4*)&acc_sh[p][tid * 4];
        s.x += pp.x; s.y += pp.y; s.z += pp.z; s.w += pp.w;
      }
      *(float4*)&out_ct[b * kH + tid * 4] = s;
    }
  } else {
    const int rr = blockIdx.x - 64;
    const int b = rr >> 2, sl = rr & 3;
    __shared__ float one_sh[64];
    __shared__ float part2[8][256];
    if (tid < 64) {
      const int n = sl * 64 + tid;
      float one = 0.f;
#pragma unroll
      for (int p = 0; p < 4; ++p) one += fp1[((size_t)(b * 4 + p)) * kNK + n];
      one_sh[tid] = one;
      atomicAdd(&out_flow[b * kNK + n],
                (attn_node[b * kNK + n] + one) * 0.33333f);
    }
    __syncthreads();
    const int m4 = (tid & 63) * 4, nsub = tid >> 6;
    float4 acc = {0.f, 0.f, 0.f, 0.f};
    const float* g =
        graph + ((size_t)(b * kNK + sl * 64 + nsub * 8)) * kNK + m4;
#pragma unroll
    for (int n = 0; n < 8; ++n) {
      float4 gg = *(const float4*)(g + (size_t)n * kNK);
      const float w = one_sh[sl * 0 + nsub * 8 + n];
      acc.x = fmaf(w, gg.x, acc.x); acc.y = fmaf(w, gg.y, acc.y);
      acc.z = fmaf(w, gg.z, acc.z); acc.w = fmaf(w, gg.w, acc.w);
    }
    *(float4*)&part2[nsub][m4] = acc;
    __syncthreads();
    if (tid < 64) {
      float4 s = {0.f, 0.f, 0.f, 0.f};
#pragma unroll
      for (int p = 0; p < 8; ++p) {
        float4 pp = *(const float4*)&part2[p][tid * 4];
        s.x += pp.x; s.y += pp.y; s.z += pp.z; s.w += pp.w;
      }
      float* dst = &out_flow[b * kNK + tid * 4];
      atomicAdd(dst + 0, s.x * 0.33333f);
      atomicAdd(dst + 1, s.y * 0.33333f);
      atomicAdd(dst + 2, s.z * 0.33333f);
      atomicAdd(dst + 3, s.w * 0.33333f);
    }
  }
}

// ---------------------------------------------------------------- launch
extern "C" void kernel_launch(void* const* d_in, const int* in_sizes, int n_in,
                              void* d_out, int out_size, void* d_ws, size_t ws_size,
                              hipStream_t stream) {
  (void)in_sizes; (void)n_in; (void)out_size; (void)ws_size;
  const float* s_t_hat  = (const float*)d_in[0];
  const float* enc_tok  = (const float*)d_in[1];
  const float* enc_node = (const float*)d_in[2];
  const int*   n2t      = (const int*)d_in[3];
  const float* mask_tok = (const float*)d_in[4];
  const float* mask_nd  = (const float*)d_in[5];
  const float* graph    = (const float*)d_in[6];
  const float* flow     = (const float*)d_in[7];
  const float* W_c      = (const float*)d_in[8];
  const float* W_tok    = (const float*)d_in[9];
  const float* W_node   = (const float*)d_in[10];
  const float* W_dec    = (const float*)d_in[11];
  const float* b_dec    = (const float*)d_in[12];
  const float* v_tok    = (const float*)d_in[13];
  const float* v_node   = (const float*)d_in[14];

  float* out = (float*)d_out;   // c_t | final_attn | attn_dist_node | flow_out
  float* out_ct        = out;
  float* out_final     = out + kB * kH;
  float* out_attn_node = out + 2 * kB * kH;
  float* out_flow      = out_attn_node + kB * kNK;

  // workspace (float offsets):
  float* ws = (float*)d_ws;
  float* scores_tok  = ws;                    // 32768
  float* scores_node = ws + 32768;            // 16384
  float* dec_part    = ws + 49152;            // 262144 (consumed by scores)
  float* ctp         = dec_part;              // alias: 64*8*512 = 262144
  float* fp1         = ws + 311296;           // 64*4*256 = 65536
  unsigned short* WtokT  = (unsigned short*)(ws + 376832);
  unsigned short* WnodeT = WtokT + kH * kH;

  prep_kernel<<<1024, 256, 0, stream>>>(W_tok, W_node, WtokT, WnodeT,
                                        s_t_hat, W_dec, dec_part);
  scores_fused_kernel<<<kTokBlocks + kNodeBlocks, 512, 0, stream>>>(
      enc_tok, enc_node, WtokT, WnodeT, dec_part, b_dec, flow, W_c,
      v_tok, v_node, scores_tok, scores_node);
  softmax_mix_kernel<<<kB, 512, 0, stream>>>(scores_node, scores_tok, n2t,
                                             mask_tok, mask_nd, out_final,
                                             out_attn_node, out_flow);
  ct_flow1_kernel<<<768, 512, 0, stream>>>(out_final, enc_tok, out_attn_node,
                                           graph, ctp, fp1);
  ct_flow2_kernel<<<320, 512, 0, stream>>>(ctp, fp1, out_attn_node, graph,
                                           out_ct, out_flow);
}

// Round 5
// 228.046 us; speedup vs baseline: 3.6967x; 1.0345x over previous
//
#include <hip/hip_runtime.h>
#include <math.h>

// Problem constants (reference: B=64, TK=512, NK=256, H=512, fp32 in/out)
constexpr int kB = 64;
constexpr int kTK = 512;
constexpr int kNK = 256;
constexpr int kH = 512;
constexpr int kTokBlocks = kB * kTK / 64;   // 512
constexpr int kNodeBlocks = kB * kNK / 64;  // 256

typedef float f32x4 __attribute__((ext_vector_type(4)));
typedef __bf16 bf16x8 __attribute__((ext_vector_type(8)));

__device__ __forceinline__ unsigned short f32_to_bf16(float f) {
  return (unsigned short)((__float_as_uint(f) + 0x8000u) >> 16);
}

__device__ __forceinline__ unsigned pk_bf16x2(float lo, float hi) {
  return (unsigned)f32_to_bf16(lo) | ((unsigned)f32_to_bf16(hi) << 16);
}

__device__ __forceinline__ float tanh_fast(float x) {
  float e = __builtin_amdgcn_exp2f(x * 2.8853900817779268f);  // e^{2x}
  return 1.0f - 2.0f * __builtin_amdgcn_rcpf(e + 1.0f);
}

// Async global->LDS, 16B per lane. LDS dest = wave-uniform base + lane*16;
// global source is per-lane (guide §5 / m97, +67% on the GEMM ladder).
__device__ __forceinline__ void gload_lds16(const void* g, void* l) {
  __builtin_amdgcn_global_load_lds(
      (__attribute__((address_space(1))) void*)(g),
      (__attribute__((address_space(3))) void*)(l), 16, 0, 0);
}

// ---------------------------------------------------------- prep kernel
// blocks [0,512): W transpose->bf16 [n][k]; blocks [512,1024): dec partials.
__global__ __launch_bounds__(256) void prep_kernel(
    const float* __restrict__ Wtok, const float* __restrict__ Wnode,
    unsigned short* __restrict__ WtokT, unsigned short* __restrict__ WnodeT,
    const float* __restrict__ s_t_hat, const float* __restrict__ W_dec,
    float* __restrict__ dec_part) {
  __shared__ float sm[32 * 33];
  const int tid = threadIdx.x;
  if (blockIdx.x < 512) {
    const int idx = blockIdx.x;
    const int z = idx >> 8, rem = idx & 255;
    const int bx = rem & 15, by = rem >> 4;
    const float* W = z ? Wnode : Wtok;
    unsigned short* T = z ? WnodeT : WtokT;
    const int tx = tid & 31, ty = tid >> 5;
#pragma unroll
    for (int i = 0; i < 4; ++i)
      sm[(ty + 8 * i) * 33 + tx] =
          W[(size_t)(by * 32 + ty + 8 * i) * kH + bx * 32 + tx];
    __syncthreads();
#pragma unroll
    for (int i = 0; i < 4; ++i)
      T[(size_t)(bx * 32 + ty + 8 * i) * kH + by * 32 + tx] =
          f32_to_bf16(sm[tx * 33 + ty + 8 * i]);
  } else {
    const int r = blockIdx.x - 512;
    const int b = r >> 3, s = r & 7;
    if (tid < 128) sm[tid] = s_t_hat[(size_t)b * 1024 + s * 128 + tid];
    __syncthreads();
    float a0 = 0.f, a1 = 0.f;
    const float* w = W_dec + (size_t)(s * 128) * kH;
#pragma unroll 8
    for (int k = 0; k < 128; ++k) {
      a0 = fmaf(sm[k], w[(size_t)k * kH + tid], a0);
      a1 = fmaf(sm[k], w[(size_t)k * kH + tid + 256], a1);
    }
    dec_part[(size_t)(b * 8 + s) * kH + tid] = a0;
    dec_part[(size_t)(b * 8 + s) * kH + tid + 256] = a1;
  }
}

// ---------------------------------------------------------- fused scores
// 512 threads = 8 waves. Block tile 64 rows x 512 cols, BK=64, 8 chunks.
// Wave w owns cols [64w,64w+64): 4(m) x 4(n) tiles of mfma 16x16x32_bf16.
// A staged as RAW F32 via global_load_lds (16B/lane): no VALU staging, no
// staging registers (rounds 0-4 were all VALU/latency-bound on staging at
// ~10% MfmaUtil regardless of schedule). f32->bf16 conversion happens at
// frag-read time (2x ds_read_b128 + ~20 VALU per frag, overlaps MFMA).
// Swizzle rule #21 (both-sides-or-neither): LDS dest linear [64][64]f32,
// global SOURCE pre-swizzled seg^=(row&7), frag READ applies the same XOR.
// Per-ds_read bank occupancy = 8 words/bank (verified by hand) = balanced.
// Registers: acc 64 (AGPR) + bbuf 16 + frag temps ~32 transient + addr ~12
// -> fits the 128 cap of (512,4): 2 blocks/CU resident.
__global__ __launch_bounds__(512, 4) void scores_fused_kernel(
    const float* __restrict__ enc_tok, const float* __restrict__ enc_node,
    const unsigned short* __restrict__ WtokT,
    const unsigned short* __restrict__ WnodeT,
    const float* __restrict__ dec_part, const float* __restrict__ b_dec,
    const float* __restrict__ flow, const float* __restrict__ W_c,
    const float* __restrict__ v_tok, const float* __restrict__ v_node,
    float* __restrict__ scores_tok, float* __restrict__ scores_node) {
  const int tid = threadIdx.x;
  const int wave = tid >> 6, lane = tid & 63;
  const int quad = lane >> 4, l15 = lane & 15;
  const bool is_node = blockIdx.x >= kTokBlocks;
  const int bidx = is_node ? (int)blockIdx.x - kTokBlocks : (int)blockIdx.x;
  const float* A = is_node ? enc_node : enc_tok;
  const unsigned short* WT = is_node ? WnodeT : WtokT;
  const float* v = is_node ? v_node : v_tok;
  float* scores = is_node ? scores_node : scores_tok;
  const int ROWS = is_node ? kNK : kTK;
  const int b = is_node ? (bidx >> 2) : (bidx >> 3);
  const int row0 = (is_node ? (bidx & 3) : (bidx & 7)) * 64;

  __shared__ __align__(16) float As32[2][4096];  // 16 KB x2, [64 rows][64 k]
  __shared__ float red[8][64];

  const f32x4 fzero = {0.f, 0.f, 0.f, 0.f};
  f32x4 acc[4][4];
#pragma unroll
  for (int i = 0; i < 4; ++i)
#pragma unroll
    for (int j = 0; j < 4; ++j) acc[i][j] = fzero;

  // --- A staging via global_load_lds --------------------------------
  // Two 8KB halves per chunk. Half s, wave w stages rows s*32+w*4 .. +3.
  // lane l -> local row lrow = s*32 + w*4 + (l>>4), seg (l&15), where the
  // GLOBAL seg is (l&15) ^ (lrow&7)  [source pre-swizzle].
  const int lrow0 = wave * 4 + (lane >> 4);           // half 0 local row
  const int gseg0 = (lane & 15) ^ (lrow0 & 7);
  const int lrow1 = 32 + lrow0;                       // half 1 local row
  const int gseg1 = (lane & 15) ^ (lrow1 & 7);
  const float* asrc0 = A + (size_t)(b * ROWS + row0 + lrow0) * kH + gseg0 * 4;
  const float* asrc1 = A + (size_t)(b * ROWS + row0 + lrow1) * kH + gseg1 * 4;
  auto stage = [&](int kc, int buf) {
    gload_lds16(asrc0 + kc * 64, &As32[buf][(wave * 4) * 64]);
    gload_lds16(asrc1 + kc * 64, &As32[buf][(32 + wave * 4) * 64]);
  };

  // --- frag read: f32 (swizzled) -> bf16x8 --------------------------
  // A-frag for 16x16x32: row = l15 (+16*mi), k = quad*8 + j  (j=0..7).
  // f32 seg pair: q2 = khalf*8 + quad*2, segs {q2, q2+1}, each XOR (row&7).
  auto readfrag = [&](int buf, int khalf, int mi) {
    const int row = mi * 16 + l15;
    const int rw = row & 7;
    const int q2 = khalf * 8 + quad * 2;
    const f32x4 a = *(const f32x4*)&As32[buf][row * 64 + ((q2 ^ rw) << 2)];
    const f32x4 c = *(const f32x4*)&As32[buf][row * 64 + (((q2 + 1) ^ rw) << 2)];
    union { bf16x8 v; unsigned u[4]; } t;
    t.u[0] = pk_bf16x2(a[0], a[1]);
    t.u[1] = pk_bf16x2(a[2], a[3]);
    t.u[2] = pk_bf16x2(c[0], c[1]);
    t.u[3] = pk_bf16x2(c[2], c[3]);
    return t.v;
  };

  // B: wave owns cols [64w, 64w+64): 4 n-tiles of 16, consumed in 2 phases.
  const int n0 = wave * 64;
  const unsigned short* bbase = WT + (size_t)(n0 + l15) * kH + quad * 8;
  bf16x8 bbuf[2][2];  // set0 = n-tiles {0,1}, set1 = n-tiles {2,3}
  auto loadB = [&](int sb, int g, int half) {
    bbuf[sb][0] = *(const bf16x8*)(bbase + (size_t)(16 * (2 * half + 0)) * kH + g * 32);
    bbuf[sb][1] = *(const bf16x8*)(bbase + (size_t)(16 * (2 * half + 1)) * kH + g * 32);
  };

  stage(0, 0);
  loadB(0, 0, 0);
  loadB(1, 0, 1);
  __syncthreads();  // drains stage(0) (vmcnt 0) + barrier

#pragma unroll
  for (int kc = 0; kc < 8; ++kc) {
    if (kc < 7) stage(kc + 1, (kc + 1) & 1);  // issue early; lands during compute
#pragma unroll
    for (int khalf = 0; khalf < 2; ++khalf) {
      const int g = kc * 2 + khalf;
      bf16x8 afr[4];
#pragma unroll
      for (int mi = 0; mi < 4; ++mi) afr[mi] = readfrag(kc & 1, khalf, mi);
      // phase 0: n-tiles 0,1 from set0; refill set1 with (g, phase1)
      if (g > 0) loadB(1, g, 1);
      __builtin_amdgcn_s_setprio(1);
#pragma unroll
      for (int mi = 0; mi < 4; ++mi)
#pragma unroll
        for (int ni = 0; ni < 2; ++ni)
          acc[mi][ni] = __builtin_amdgcn_mfma_f32_16x16x32_bf16(
              afr[mi], bbuf[0][ni], acc[mi][ni], 0, 0, 0);
      __builtin_amdgcn_s_setprio(0);
      // phase 1: n-tiles 2,3 from set1; refill set0 with (g+1, phase0)
      if (g < 15) loadB(0, g + 1, 0);
      __builtin_amdgcn_s_setprio(1);
#pragma unroll
      for (int mi = 0; mi < 4; ++mi)
#pragma unroll
        for (int ni = 0; ni < 2; ++ni)
          acc[mi][ni + 2] = __builtin_amdgcn_mfma_f32_16x16x32_bf16(
              afr[mi], bbuf[1][ni], acc[mi][ni + 2], 0, 0, 0);
      __builtin_amdgcn_s_setprio(0);
    }
    __syncthreads();  // chunk boundary; drains stage(kc+1), issued a chunk ago
  }

  // epilogue; C/D: col = n0+16ni+l15, row = 16mi+quad*4+reg
  float dec2[4], vv2[4], wc2[4];
#pragma unroll
  for (int ni = 0; ni < 4; ++ni) {
    const int col = n0 + 16 * ni + l15;
    float d = b_dec[col];
#pragma unroll
    for (int p = 0; p < 8; ++p) d += dec_part[(size_t)(b * 8 + p) * kH + col];
    dec2[ni] = d;
    vv2[ni] = v[col];
    wc2[ni] = is_node ? W_c[col] : 0.f;
  }
#pragma unroll
  for (int mi = 0; mi < 4; ++mi) {
#pragma unroll
    for (int reg = 0; reg < 4; ++reg) {
      const int row = 16 * mi + quad * 4 + reg;
      const float fl = is_node ? flow[b * kNK + row0 + row] : 0.f;
      float p = 0.f;
#pragma unroll
      for (int ni = 0; ni < 4; ++ni)
        p += tanh_fast(fmaf(fl, wc2[ni], acc[mi][ni][reg] + dec2[ni])) * vv2[ni];
#pragma unroll
      for (int off = 1; off < 16; off <<= 1) p += __shfl_xor(p, off, 64);
      if (l15 == 0) red[wave][row] = p;
    }
  }
  __syncthreads();
  if (tid < 64) {
    float s = 0.f;
#pragma unroll
    for (int w = 0; w < 8; ++w) s += red[w][tid];
    scores[b * ROWS + row0 + tid] = s;
  }
}

// ---------------------------------------------------------- softmax/mix (+zero flow)
__device__ __forceinline__ float block_sum_512(float v, float* rbuf) {
#pragma unroll
  for (int off = 32; off >= 1; off >>= 1) v += __shfl_xor(v, off, 64);
  if ((threadIdx.x & 63) == 0) rbuf[threadIdx.x >> 6] = v;
  __syncthreads();
  float s = rbuf[0];
#pragma unroll
  for (int w = 1; w < 8; ++w) s += rbuf[w];
  __syncthreads();
  return s;
}

__global__ __launch_bounds__(512) void softmax_mix_kernel(
    const float* __restrict__ scores_node, const float* __restrict__ scores_tok,
    const int* __restrict__ node_to_token,
    const float* __restrict__ mask_tok, const float* __restrict__ mask_node,
    float* __restrict__ out_final, float* __restrict__ out_attn_node,
    float* __restrict__ out_flow) {
  const int b = blockIdx.x, tid = threadIdx.x;
  __shared__ float an_sh[kNK];
  __shared__ float rbuf[8];

  if (tid < kNK) out_flow[b * kNK + tid] = 0.f;  // init for flow2 atomics

  float en = 0.f;
  if (tid < kNK)
    en = expf(scores_node[b * kNK + tid]) * mask_node[b * kNK + tid];
  float sn = block_sum_512(en, rbuf);
  float an = en / sn;
  if (tid < kNK) {
    an_sh[tid] = an;
    out_attn_node[b * kNK + tid] = an;
  }
  __syncthreads();

  const float mt = mask_tok[b * kTK + tid];
  const int idx = node_to_token[b * kTK + tid];
  float eg = expf(an_sh[idx]) * mt;
  float sg = block_sum_512(eg, rbuf);
  float an2t = eg / sg;

  float et = expf(scores_tok[b * kTK + tid]) * mt;
  float st = block_sum_512(et, rbuf);
  float at = et / st;

  out_final[b * kTK + tid] = 0.5f * (at + an2t);
}

// ---------------------------------------------------------- ct_partial + flow1
// blocks [0,512): ct partial (b, 64-row slice s of 8): 4 sub-accumulators of
//   16 rows each, reduced in LDS -> ctp[b*8+s][512].
// blocks [512,768): one_hop partials (b, sl of 64 n-rows), float4 over m,
//   in-block reduce over nsub -> fp1[b][4][256].
__global__ __launch_bounds__(512) void ct_flow1_kernel(
    const float* __restrict__ final_attn, const float* __restrict__ enc_tok,
    const float* __restrict__ attn_node, const float* __restrict__ graph,
    float* __restrict__ ctp, float* __restrict__ fp1) {
  const int tid = threadIdx.x;
  if (blockIdx.x < 512) {
    const int b = blockIdx.x >> 3, s = blockIdx.x & 7;
    __shared__ float fa[64];
    __shared__ float part[4][512];
    if (tid < 64) fa[tid] = final_attn[b * kTK + s * 64 + tid];
    __syncthreads();
    const int h4 = (tid & 127) * 4, tsub = tid >> 7;   // 4 tsubs x 16 rows
    float4 acc = {0.f, 0.f, 0.f, 0.f};
    const float* base =
        enc_tok + ((size_t)(b * kTK + s * 64 + tsub * 16)) * kH + h4;
#pragma unroll
    for (int t = 0; t < 16; ++t) {
      float4 e = *(const float4*)(base + (size_t)t * kH);
      const float w = fa[tsub * 16 + t];
      acc.x = fmaf(w, e.x, acc.x); acc.y = fmaf(w, e.y, acc.y);
      acc.z = fmaf(w, e.z, acc.z); acc.w = fmaf(w, e.w, acc.w);
    }
    *(float4*)&part[tsub][h4] = acc;
    __syncthreads();
    if (tid < 128) {
      float4 s0 = {0.f, 0.f, 0.f, 0.f};
#pragma unroll
      for (int p = 0; p < 4; ++p) {
        float4 pp = *(const float4*)&part[p][tid * 4];
        s0.x += pp.x; s0.y += pp.y; s0.z += pp.z; s0.w += pp.w;
      }
      *(float4*)&ctp[((size_t)(b * 8 + s)) * kH + tid * 4] = s0;
    }
  } else {
    const int rr = blockIdx.x - 512;
    const int b = rr >> 2, sl = rr & 3;
    __shared__ float z[64];
    __shared__ float part[8][256];
    if (tid < 64) z[tid] = attn_node[b * kNK + sl * 64 + tid];
    __syncthreads();
    const int m4 = (tid & 63) * 4, nsub = tid >> 6;
    float4 acc = {0.f, 0.f, 0.f, 0.f};
    const float* g =
        graph + ((size_t)(b * kNK + sl * 64 + nsub * 8)) * kNK + m4;
#pragma unroll
    for (int n = 0; n < 8; ++n) {
      float4 gg = *(const float4*)(g + (size_t)n * kNK);
      const float w = z[nsub * 8 + n];
      acc.x = fmaf(w, gg.x, acc.x); acc.y = fmaf(w, gg.y, acc.y);
      acc.z = fmaf(w, gg.z, acc.z); acc.w = fmaf(w, gg.w, acc.w);
    }
    *(float4*)&part[nsub][m4] = acc;
    __syncthreads();
    if (tid < 64) {
      float4 s0 = {0.f, 0.f, 0.f, 0.f};
#pragma unroll
      for (int p = 0; p < 8; ++p) {
        float4 pp = *(const float4*)&part[p][tid * 4];
        s0.x += pp.x; s0.y += pp.y; s0.z += pp.z; s0.w += pp.w;
      }
      *(float4*)&fp1[((size_t)(b * 4 + sl)) * kNK + tid * 4] = s0;
    }
  }
}

// ---------------------------------------------------------- ct_reduce + flow 2-hop
__global__ __launch_bounds__(512) void ct_flow2_kernel(
    const float* __restrict__ ctp, const float* __restrict__ fp1,
    const float* __restrict__ attn_node, const float* __restrict__ graph,
    float* __restrict__ out_ct, float* __restrict__ out_flow) {
  const int tid = threadIdx.x;
  if (blockIdx.x < 64) {
    const int b = blockIdx.x;
    __shared__ float acc_sh[4][512];
    const int h4 = (tid & 127) * 4, part = tid >> 7;
    float4 a = {0.f, 0.f, 0.f, 0.f};
#pragma unroll
    for (int j = 0; j < 2; ++j) {
      float4 c = *(const float4*)&ctp[((size_t)(b * 8 + part * 2 + j)) * kH + h4];
      a.x += c.x; a.y += c.y; a.z += c.z; a.w += c.w;
    }
    *(float4*)&acc_sh[part][h4] = a;
    __syncthreads();
    if (tid < 128) {
      float4 s = {0.f, 0.f, 0.f, 0.f};
#pragma unroll
      for (int p = 0; p < 4; ++p) {
        float4 pp = *(const float4*)&acc_sh[p][tid * 4];
        s.x += pp.x; s.y += pp.y; s.z += pp.z; s.w += pp.w;
      }
      *(float4*)&out_ct[b * kH + tid * 4] = s;
    }
  } else {
    const int rr = blockIdx.x - 64;
    const int b = rr >> 2, sl = rr & 3;
    __shared__ float one_sh[64];
    __shared__ float part2[8][256];
    if (tid < 64) {
      const int n = sl * 64 + tid;
      float one = 0.f;
#pragma unroll
      for (int p = 0; p < 4; ++p) one += fp1[((size_t)(b * 4 + p)) * kNK + n];
      one_sh[tid] = one;
      atomicAdd(&out_flow[b * kNK + n],
                (attn_node[b * kNK + n] + one) * 0.33333f);
    }
    __syncthreads();
    const int m4 = (tid & 63) * 4, nsub = tid >> 6;
    float4 acc = {0.f, 0.f, 0.f, 0.f};
    const float* g =
        graph + ((size_t)(b * kNK + sl * 64 + nsub * 8)) * kNK + m4;
#pragma unroll
    for (int n = 0; n < 8; ++n) {
      float4 gg = *(const float4*)(g + (size_t)n * kNK);
      const float w = one_sh[sl * 0 + nsub * 8 + n];
      acc.x = fmaf(w, gg.x, acc.x); acc.y = fmaf(w, gg.y, acc.y);
      acc.z = fmaf(w, gg.z, acc.z); acc.w = fmaf(w, gg.w, acc.w);
    }
    *(float4*)&part2[nsub][m4] = acc;
    __syncthreads();
    if (tid < 64) {
      float4 s = {0.f, 0.f, 0.f, 0.f};
#pragma unroll
      for (int p = 0; p < 8; ++p) {
        float4 pp = *(const float4*)&part2[p][tid * 4];
        s.x += pp.x; s.y += pp.y; s.z += pp.z; s.w += pp.w;
      }
      float* dst = &out_flow[b * kNK + tid * 4];
      atomicAdd(dst + 0, s.x * 0.33333f);
      atomicAdd(dst + 1, s.y * 0.33333f);
      atomicAdd(dst + 2, s.z * 0.33333f);
      atomicAdd(dst + 3, s.w * 0.33333f);
    }
  }
}

// ---------------------------------------------------------------- launch
extern "C" void kernel_launch(void* const* d_in, const int* in_sizes, int n_in,
                              void* d_out, int out_size, void* d_ws, size_t ws_size,
                              hipStream_t stream) {
  (void)in_sizes; (void)n_in; (void)out_size; (void)ws_size;
  const float* s_t_hat  = (const float*)d_in[0];
  const float* enc_tok  = (const float*)d_in[1];
  const float* enc_node = (const float*)d_in[2];
  const int*   n2t      = (const int*)d_in[3];
  const float* mask_tok = (const float*)d_in[4];
  const float* mask_nd  = (const float*)d_in[5];
  const float* graph    = (const float*)d_in[6];
  const float* flow     = (const float*)d_in[7];
  const float* W_c      = (const float*)d_in[8];
  const float* W_tok    = (const float*)d_in[9];
  const float* W_node   = (const float*)d_in[10];
  const float* W_dec    = (const float*)d_in[11];
  const float* b_dec    = (const float*)d_in[12];
  const float* v_tok    = (const float*)d_in[13];
  const float* v_node   = (const float*)d_in[14];

  float* out = (float*)d_out;   // c_t | final_attn | attn_dist_node | flow_out
  float* out_ct        = out;
  float* out_final     = out + kB * kH;
  float* out_attn_node = out + 2 * kB * kH;
  float* out_flow      = out_attn_node + kB * kNK;

  // workspace (float offsets):
  float* ws = (float*)d_ws;
  float* scores_tok  = ws;                    // 32768
  float* scores_node = ws + 32768;            // 16384
  float* dec_part    = ws + 49152;            // 262144 (consumed by scores)
  float* ctp         = dec_part;              // alias: 64*8*512 = 262144
  float* fp1         = ws + 311296;           // 64*4*256 = 65536
  unsigned short* WtokT  = (unsigned short*)(ws + 376832);
  unsigned short* WnodeT = WtokT + kH * kH;

  prep_kernel<<<1024, 256, 0, stream>>>(W_tok, W_node, WtokT, WnodeT,
                                        s_t_hat, W_dec, dec_part);
  scores_fused_kernel<<<kTokBlocks + kNodeBlocks, 512, 0, stream>>>(
      enc_tok, enc_node, WtokT, WnodeT, dec_part, b_dec, flow, W_c,
      v_tok, v_node, scores_tok, scores_node);
  softmax_mix_kernel<<<kB, 512, 0, stream>>>(scores_node, scores_tok, n2t,
                                             mask_tok, mask_nd, out_final,
                                             out_attn_node, out_flow);
  ct_flow1_kernel<<<768, 512, 0, stream>>>(out_final, enc_tok, out_attn_node,
                                           graph, ctp, fp1);
  ct_flow2_kernel<<<320, 512, 0, stream>>>(ctp, fp1, out_attn_node, graph,
                                           out_ct, out_flow);
}